// Round 1
// baseline (4647.470 us; speedup 1.0000x reference)
//
#include <hip/hip_runtime.h>
#include <cfloat>
#include <cmath>

// Problem constants
// B=8 S=32 P=5 C=528 H=784 M=128 N=196 tot=1280 out cols=1697

// ---------------------------------------------------------------------------
// Generic tiled GEMM: C[M,N] = A[M,K] @ Bt[N,K]^T (+bias[N])
// Bt is weights in row-major [N,K] (PyTorch Linear layout) -> no pre-transpose.
// Tiles: 32x64, K-tile 16. Thread computes 2x4 outputs.
// ---------------------------------------------------------------------------
#define GT_BM 32
#define GT_BN 64
#define GT_BK 16

__global__ __launch_bounds__(256) void gemm_nt(const float* __restrict__ A,
                                               const float* __restrict__ Bt,
                                               const float* __restrict__ bias,
                                               float* __restrict__ Cm,
                                               int Mn, int Nn, int Kn) {
  __shared__ float sA[GT_BM][GT_BK + 1];
  __shared__ float sB[GT_BK][68];   // stride 68: conflict-safe, 16B-aligned rows
  const int tid = threadIdx.x;
  const int tm = tid >> 4;   // 0..15 -> rows tm*2 + {0,1}
  const int tn = tid & 15;   // 0..15 -> cols tn*4 + {0..3}
  const int rowBase = blockIdx.y * GT_BM;
  const int colBase = blockIdx.x * GT_BN;
  float acc[2][4] = {};

  for (int k0 = 0; k0 < Kn; k0 += GT_BK) {
    for (int u = tid; u < GT_BM * GT_BK; u += 256) {
      int r = u >> 4, kk = u & 15;
      int gk = k0 + kk;
      int gr = rowBase + r;
      sA[r][kk] = (gr < Mn && gk < Kn) ? A[(size_t)gr * Kn + gk] : 0.f;
    }
    for (int u = tid; u < GT_BN * GT_BK; u += 256) {
      int n = u >> 4, kk = u & 15;
      int gk = k0 + kk, gn = colBase + n;
      sB[kk][n] = (gn < Nn && gk < Kn) ? Bt[(size_t)gn * Kn + gk] : 0.f;
    }
    __syncthreads();
#pragma unroll
    for (int kk = 0; kk < GT_BK; ++kk) {
      float a0 = sA[tm * 2 + 0][kk];
      float a1 = sA[tm * 2 + 1][kk];
      float b0 = sB[kk][tn * 4 + 0];
      float b1 = sB[kk][tn * 4 + 1];
      float b2 = sB[kk][tn * 4 + 2];
      float b3 = sB[kk][tn * 4 + 3];
      acc[0][0] += a0 * b0; acc[0][1] += a0 * b1; acc[0][2] += a0 * b2; acc[0][3] += a0 * b3;
      acc[1][0] += a1 * b0; acc[1][1] += a1 * b1; acc[1][2] += a1 * b2; acc[1][3] += a1 * b3;
    }
    __syncthreads();
  }
#pragma unroll
  for (int i = 0; i < 2; ++i) {
#pragma unroll
    for (int j = 0; j < 4; ++j) {
      int gr = rowBase + tm * 2 + i;
      int gc = colBase + tn * 4 + j;
      if (gr < Mn && gc < Nn) {
        float v = acc[i][j];
        if (bias) v += bias[gc];
        Cm[(size_t)gr * Nn + gc] = v;
      }
    }
  }
}

// ---------------------------------------------------------------------------
// GRU step: h_new[b,j] for 8*784 outputs. gtid -> (j = g>>3, b = g&7) so the
// 8 lanes sharing j broadcast the same W_hh rows (read as float4 streams).
// ---------------------------------------------------------------------------
__global__ __launch_bounds__(64) void gru_step(const float* __restrict__ GI,
                                               const float* __restrict__ Whh,
                                               const float* __restrict__ bhh,
                                               const float* __restrict__ h_in,
                                               float* __restrict__ h_out,
                                               float* __restrict__ pref, int s) {
  const int g = blockIdx.x * 64 + threadIdx.x;   // 0..6271
  const int b = g & 7;
  const int j = g >> 3;                           // 0..783
  const float* hr = h_in + b * 784;
  const float4* hv4 = (const float4*)hr;
  const float4* wr = (const float4*)(Whh + (size_t)j * 784);
  const float4* wz = (const float4*)(Whh + (size_t)(784 + j) * 784);
  const float4* wn = (const float4*)(Whh + (size_t)(1568 + j) * 784);
  float ar = 0.f, az = 0.f, an = 0.f;
#pragma unroll 4
  for (int k = 0; k < 196; ++k) {
    float4 h4 = hv4[k];
    float4 r4 = wr[k];
    float4 z4 = wz[k];
    float4 n4 = wn[k];
    ar += h4.x * r4.x + h4.y * r4.y + h4.z * r4.z + h4.w * r4.w;
    az += h4.x * z4.x + h4.y * z4.y + h4.z * z4.z + h4.w * z4.w;
    an += h4.x * n4.x + h4.y * n4.y + h4.z * n4.z + h4.w * n4.w;
  }
  const int bs = b * 32 + s;
  const float* gi = GI + (size_t)bs * 2352;
  float gir = gi[j], giz = gi[784 + j], gin = gi[1568 + j];
  float ghr = ar + bhh[j];
  float ghz = az + bhh[784 + j];
  float ghn = an + bhh[1568 + j];
  float r = 1.f / (1.f + expf(-(gir + ghr)));
  float z = 1.f / (1.f + expf(-(giz + ghz)));
  float n = tanhf(gin + r * ghn);
  float hprev = hr[j];
  float hn = (1.f - z) * n + z * hprev;
  h_out[b * 784 + j] = hn;
  pref[(size_t)bs * 784 + j] = hn;
}

// ---------------------------------------------------------------------------
// Motion BN stats over the 256 distinct rows (duplication over P is uniform,
// so stats over 256 == stats over 1280).
// ---------------------------------------------------------------------------
__global__ __launch_bounds__(128) void mot_stats(const float* __restrict__ mot,
                                                 float* __restrict__ msum,
                                                 float* __restrict__ msq) {
  int m = threadIdx.x;   // 0..127
  float s = 0.f, q = 0.f;
  for (int r = 0; r < 256; ++r) {
    float v = mot[r * 128 + m];
    s += v;
    q += v * v;
  }
  msum[m] = s;
  msq[m] = q;
}

// ---------------------------------------------------------------------------
// Pass 1: fused scores.  Per block t:
//   A[m,n] = sum_c Wv_w[m,c]*video[t,c,n]   (128x196 GEMM, K=528)
//   scores[t,n] = Wpv_b + sum_m Wpv_w[m]*tanh(A[m,n] + Wv_b[m] + p_att[bs,m])
// Thread (tm,tn) owns m = tm+16i (i<8), n = tn+16j (j<13); n padded to 208.
// ---------------------------------------------------------------------------
__global__ __launch_bounds__(256, 1) void attn_scores(
    const float* __restrict__ video, const float* __restrict__ Wv,
    const float* __restrict__ Wvb, const float* __restrict__ patt,
    const float* __restrict__ Wpv, const float* __restrict__ Wpvb,
    float* __restrict__ scores) {
  __shared__ float sW[16 * 132];
  __shared__ float sV[16 * 208];
  __shared__ float pa[128];
  __shared__ float wpv[128];
  __shared__ float ssc[208];

  const int t = blockIdx.x;
  const int bs = t / 5;
  const int tid = threadIdx.x;
  const int tm = tid & 15;
  const int tn = tid >> 4;

  if (tid < 128) {
    pa[tid] = Wvb[tid] + patt[(size_t)bs * 128 + tid];
    wpv[tid] = Wpv[tid];
  }
  for (int u = tid; u < 208; u += 256) ssc[u] = 0.f;

  float acc[8][13] = {};
  const float* vbase = video + (size_t)t * 103488;

  for (int c0 = 0; c0 < 528; c0 += 16) {
    for (int u = tid; u < 2048; u += 256) {       // W tile: sW[kk][m]
      int m = u >> 4, kk = u & 15;
      sW[kk * 132 + m] = Wv[(size_t)m * 528 + c0 + kk];
    }
    for (int u = tid; u < 16 * 208; u += 256) {   // V tile: sV[kk][n]
      int kk = u / 208;
      int n = u - kk * 208;
      sV[kk * 208 + n] = (n < 196) ? vbase[(size_t)(c0 + kk) * 196 + n] : 0.f;
    }
    __syncthreads();
#pragma unroll
    for (int kk = 0; kk < 16; ++kk) {
      float a[8], bb[13];
#pragma unroll
      for (int i = 0; i < 8; ++i) a[i] = sW[kk * 132 + tm + 16 * i];
#pragma unroll
      for (int j = 0; j < 13; ++j) bb[j] = sV[kk * 208 + tn + 16 * j];
#pragma unroll
      for (int i = 0; i < 8; ++i)
#pragma unroll
        for (int j = 0; j < 13; ++j) acc[i][j] += a[i] * bb[j];
    }
    __syncthreads();
  }

  float contrib[13] = {};
#pragma unroll
  for (int i = 0; i < 8; ++i) {
    int m = tm + 16 * i;
    float bias = pa[m];
    float w = wpv[m];
#pragma unroll
    for (int j = 0; j < 13; ++j) contrib[j] += tanhf(acc[i][j] + bias) * w;
  }
#pragma unroll
  for (int j = 0; j < 13; ++j) atomicAdd(&ssc[tn + 16 * j], contrib[j]);
  __syncthreads();
  if (tid < 196) scores[(size_t)t * 196 + tid] = ssc[tid] + Wpvb[0];
}

// ---------------------------------------------------------------------------
// Pass 2: softmax over n, then 1x1 conv on the OTHER view of the same buffer:
//   pre[o,n] = att[n] * sum_c conv_w[o,c]*video_flat[t, n*528+c] + conv_b[o]
// Writes pre to ws and accumulates global BN stats (sum, sumsq per channel).
// ---------------------------------------------------------------------------
__global__ __launch_bounds__(256) void attn_conv(
    const float* __restrict__ video, const float* __restrict__ scores,
    const float* __restrict__ convw, const float* __restrict__ convb,
    float* __restrict__ vid_pre, float* __restrict__ vstats) {
  __shared__ float red[256];
  __shared__ float att[196];
  __shared__ float scw[4 * 528];
  __shared__ float pre[784];

  const int t = blockIdx.x;
  const int tid = threadIdx.x;
  for (int u = tid; u < 2112; u += 256) scw[u] = convw[u];

  float v = (tid < 196) ? scores[(size_t)t * 196 + tid] : -FLT_MAX;
  red[tid] = v;
  __syncthreads();
  for (int st = 128; st > 0; st >>= 1) {
    if (tid < st) red[tid] = fmaxf(red[tid], red[tid + st]);
    __syncthreads();
  }
  float mx = red[0];
  __syncthreads();
  float e = (tid < 196) ? expf(v - mx) : 0.f;
  red[tid] = e;
  __syncthreads();
  for (int st = 128; st > 0; st >>= 1) {
    if (tid < st) red[tid] += red[tid + st];
    __syncthreads();
  }
  float tot = red[0];
  if (tid < 196) att[tid] = e / tot;
  __syncthreads();

  const int lane = tid & 63;
  const int wv = tid >> 6;
  const float* vb = video + (size_t)t * 103488;
  for (int n = wv; n < 196; n += 4) {
    float s0 = 0.f, s1 = 0.f, s2 = 0.f, s3 = 0.f;
    for (int c = lane; c < 528; c += 64) {
      float x = vb[(size_t)n * 528 + c];
      s0 += x * scw[c];
      s1 += x * scw[528 + c];
      s2 += x * scw[1056 + c];
      s3 += x * scw[1584 + c];
    }
#pragma unroll
    for (int off = 32; off > 0; off >>= 1) {
      s0 += __shfl_down(s0, off);
      s1 += __shfl_down(s1, off);
      s2 += __shfl_down(s2, off);
      s3 += __shfl_down(s3, off);
    }
    if (lane == 0) {
      float a = att[n];
      pre[0 * 196 + n] = a * s0 + convb[0];
      pre[1 * 196 + n] = a * s1 + convb[1];
      pre[2 * 196 + n] = a * s2 + convb[2];
      pre[3 * 196 + n] = a * s3 + convb[3];
    }
  }
  __syncthreads();

  // write pre + accumulate channel stats (wave shuffle reduce, 8 atomics/wave)
  float ls[4] = {0.f, 0.f, 0.f, 0.f};
  float lq[4] = {0.f, 0.f, 0.f, 0.f};
  for (int u = tid; u < 784; u += 256) {
    float x = pre[u];
    vid_pre[(size_t)t * 784 + u] = x;
    int o = u / 196;
#pragma unroll
    for (int oo = 0; oo < 4; ++oo) {
      ls[oo] += (o == oo) ? x : 0.f;
      lq[oo] += (o == oo) ? x * x : 0.f;
    }
  }
#pragma unroll
  for (int oo = 0; oo < 4; ++oo) {
#pragma unroll
    for (int off = 32; off > 0; off >>= 1) {
      ls[oo] += __shfl_down(ls[oo], off);
      lq[oo] += __shfl_down(lq[oo], off);
    }
  }
  if (lane == 0) {
#pragma unroll
    for (int oo = 0; oo < 4; ++oo) {
      atomicAdd(&vstats[oo], ls[oo]);
      atomicAdd(&vstats[4 + oo], lq[oo]);
    }
  }
}

// ---------------------------------------------------------------------------
// Pass 3: assemble output [1280, 1697] = [tw | pref(784) | motBN(128) | vidBN(784)]
// ---------------------------------------------------------------------------
__global__ __launch_bounds__(256) void finalize(
    const float* __restrict__ tw, const float* __restrict__ prefb,
    const float* __restrict__ motl, const float* __restrict__ msum,
    const float* __restrict__ msq, const float* __restrict__ mg,
    const float* __restrict__ mb, const float* __restrict__ vid_pre,
    const float* __restrict__ vstats, const float* __restrict__ vg,
    const float* __restrict__ vbb, float* __restrict__ out) {
  int g = blockIdx.x * 256 + threadIdx.x;
  if (g >= 1280 * 1697) return;
  int t = g / 1697;
  int col = g - t * 1697;
  int bs = t / 5;
  int p = t - bs * 5;
  float r;
  if (col == 0) {
    r = tw[p];
  } else if (col < 785) {
    r = prefb[(size_t)bs * 784 + (col - 1)];
  } else if (col < 913) {
    int m = col - 785;
    float x = motl[(size_t)bs * 128 + m];
    float mu = msum[m] * (1.f / 256.f);
    float var = msq[m] * (1.f / 256.f) - mu * mu;
    float y = (x - mu) * rsqrtf(var + 1e-5f) * mg[m] + mb[m];
    r = fmaxf(y, 0.f);
  } else {
    int q = col - 913;
    int o = q / 196;
    float x = vid_pre[(size_t)t * 784 + q];
    float mu = vstats[o] * (1.f / 250880.f);
    float var = vstats[4 + o] * (1.f / 250880.f) - mu * mu;
    float y = (x - mu) * rsqrtf(var + 1e-5f) * vg[o] + vbb[o];
    r = fmaxf(y, 0.f);
  }
  out[g] = r;
}

// ---------------------------------------------------------------------------
extern "C" void kernel_launch(void* const* d_in, const int* in_sizes, int n_in,
                              void* d_out, int out_size, void* d_ws,
                              size_t ws_size, hipStream_t stream) {
  const float* fov = (const float*)d_in[0];     // [8,32,528]
  const float* motion = (const float*)d_in[1];  // [8,32,1,90] -> [256,90]
  const float* video = (const float*)d_in[2];   // [1280,528,196] flat
  const float* timew = (const float*)d_in[3];   // [5]
  const float* w_ih = (const float*)d_in[4];    // [2352,528]
  const float* w_hh = (const float*)d_in[5];    // [2352,784]
  const float* b_ih = (const float*)d_in[6];
  const float* b_hh = (const float*)d_in[7];
  const float* Wp = (const float*)d_in[8];      // [128,784]
  const float* Wv_w = (const float*)d_in[9];    // [128,528]
  const float* Wv_b = (const float*)d_in[10];
  const float* Wpv_w = (const float*)d_in[11];  // [1,128]
  const float* Wpv_b = (const float*)d_in[12];
  const float* conv_w = (const float*)d_in[13]; // [4,528]
  const float* conv_b = (const float*)d_in[14];
  const float* vbn_g = (const float*)d_in[15];
  const float* vbn_b = (const float*)d_in[16];
  const float* me_w = (const float*)d_in[17];   // [128,90]
  const float* me_b = (const float*)d_in[18];
  const float* mbn_g = (const float*)d_in[19];
  const float* mbn_b = (const float*)d_in[20];

  float* ws = (float*)d_ws;
  // workspace layout (floats)
  float* h0b = ws + 0;            // 6272
  float* stats = ws + 6272;       // 264 = msum(128) msq(128) vstats(8)
  float* msum = stats;
  float* msq = stats + 128;
  float* vstats = stats + 256;
  float* h1b = ws + 6656;         // 6272
  float* GI = ws + 12928;         // 256*2352 = 602112
  float* prefb = ws + 615040;     // 256*784 = 200704
  float* patt = ws + 815744;      // 256*128
  float* motl = ws + 848512;      // 256*128
  float* scores = ws + 881280;    // 1280*196 = 250880
  float* vid_pre = ws + 1132160;  // 1280*784 = 1003520  (total 8.55 MB)

  // zero h0 + all stats accumulators in one memset
  hipMemsetAsync(ws, 0, 6536 * sizeof(float), stream);

  // GRU input projection: GI[256,2352] = fov @ w_ih^T + b_ih
  gemm_nt<<<dim3((2352 + GT_BN - 1) / GT_BN, 256 / GT_BM), 256, 0, stream>>>(
      fov, w_ih, b_ih, GI, 256, 2352, 528);

  // GRU recurrence (ping-pong h buffers)
  for (int s = 0; s < 32; ++s) {
    const float* hin = (s & 1) ? h1b : h0b;
    float* hout = (s & 1) ? h0b : h1b;
    gru_step<<<98, 64, 0, stream>>>(GI, w_hh, b_hh, hin, hout, prefb, s);
  }

  // p_att[256,128] = pref @ Wp^T
  gemm_nt<<<dim3(2, 8), 256, 0, stream>>>(prefb, Wp, nullptr, patt, 256, 128, 784);
  // mot_lin[256,128] = motion @ me_w^T + me_b
  gemm_nt<<<dim3(2, 8), 256, 0, stream>>>(motion, me_w, me_b, motl, 256, 128, 90);
  mot_stats<<<1, 128, 0, stream>>>(motl, msum, msq);

  attn_scores<<<1280, 256, 0, stream>>>(video, Wv_w, Wv_b, patt, Wpv_w, Wpv_b,
                                        scores);
  attn_conv<<<1280, 256, 0, stream>>>(video, scores, conv_w, conv_b, vid_pre,
                                      vstats);

  int total = 1280 * 1697;
  finalize<<<(total + 255) / 256, 256, 0, stream>>>(
      timew, prefb, motl, msum, msq, mbn_g, mbn_b, vid_pre, vstats, vbn_g,
      vbn_b, (float*)d_out);
}

// Round 2
// 3161.386 us; speedup vs baseline: 1.4701x; 1.4701x over previous
//
#include <hip/hip_runtime.h>
#include <cfloat>
#include <cmath>

// B=8 S=32 P=5 C=528 H=784 M=128 N=196 tot=1280 out cols=1697

typedef __attribute__((ext_vector_type(8))) short short8;
typedef __attribute__((ext_vector_type(4))) float f32x4;

__device__ __forceinline__ unsigned bf16r(float f) {
  union { float f; unsigned u; } v;
  v.f = f;
  unsigned u = v.u;
  u += 0x7fffu + ((u >> 16) & 1u);   // round-to-nearest-even
  return u >> 16;
}

__device__ __forceinline__ float tanh_fast(float x) {
  float e = __expf(2.f * x);
  return 1.f - 2.f / (e + 1.f);
}

// ---------------------------------------------------------------------------
// Generic tiled GEMM: C[M,N] = A[M,K] @ Bt[N,K]^T (+bias[N]) — fp32, small use
// ---------------------------------------------------------------------------
#define GT_BM 32
#define GT_BN 64
#define GT_BK 16

__global__ __launch_bounds__(256) void gemm_nt(const float* __restrict__ A,
                                               const float* __restrict__ Bt,
                                               const float* __restrict__ bias,
                                               float* __restrict__ Cm,
                                               int Mn, int Nn, int Kn) {
  __shared__ float sA[GT_BM][GT_BK + 1];
  __shared__ float sB[GT_BK][68];
  const int tid = threadIdx.x;
  const int tm = tid >> 4;
  const int tn = tid & 15;
  const int rowBase = blockIdx.y * GT_BM;
  const int colBase = blockIdx.x * GT_BN;
  float acc[2][4] = {};

  for (int k0 = 0; k0 < Kn; k0 += GT_BK) {
    for (int u = tid; u < GT_BM * GT_BK; u += 256) {
      int r = u >> 4, kk = u & 15;
      int gk = k0 + kk, gr = rowBase + r;
      sA[r][kk] = (gr < Mn && gk < Kn) ? A[(size_t)gr * Kn + gk] : 0.f;
    }
    for (int u = tid; u < GT_BN * GT_BK; u += 256) {
      int n = u >> 4, kk = u & 15;
      int gk = k0 + kk, gn = colBase + n;
      sB[kk][n] = (gn < Nn && gk < Kn) ? Bt[(size_t)gn * Kn + gk] : 0.f;
    }
    __syncthreads();
#pragma unroll
    for (int kk = 0; kk < GT_BK; ++kk) {
      float a0 = sA[tm * 2 + 0][kk];
      float a1 = sA[tm * 2 + 1][kk];
      float b0 = sB[kk][tn * 4 + 0];
      float b1 = sB[kk][tn * 4 + 1];
      float b2 = sB[kk][tn * 4 + 2];
      float b3 = sB[kk][tn * 4 + 3];
      acc[0][0] += a0 * b0; acc[0][1] += a0 * b1; acc[0][2] += a0 * b2; acc[0][3] += a0 * b3;
      acc[1][0] += a1 * b0; acc[1][1] += a1 * b1; acc[1][2] += a1 * b2; acc[1][3] += a1 * b3;
    }
    __syncthreads();
  }
#pragma unroll
  for (int i = 0; i < 2; ++i)
#pragma unroll
    for (int j = 0; j < 4; ++j) {
      int gr = rowBase + tm * 2 + i;
      int gc = colBase + tn * 4 + j;
      if (gr < Mn && gc < Nn) {
        float v = acc[i][j];
        if (bias) v += bias[gc];
        Cm[(size_t)gr * Nn + gc] = v;
      }
    }
}

// ---------------------------------------------------------------------------
// Whh [2352,784] -> WhhT [784,2352]
// ---------------------------------------------------------------------------
__global__ __launch_bounds__(256) void whh_transpose(const float* __restrict__ W,
                                                     float* __restrict__ WT) {
  __shared__ float tile[32][33];
  const int n0 = blockIdx.x * 32;
  const int k0 = blockIdx.y * 32;
  const int tx = threadIdx.x & 31;
  const int ty = threadIdx.x >> 5;
  for (int i = ty; i < 32; i += 8) {
    int n = n0 + i, k = k0 + tx;
    tile[i][tx] = (n < 2352 && k < 784) ? W[(size_t)n * 784 + k] : 0.f;
  }
  __syncthreads();
  for (int i = ty; i < 32; i += 8) {
    int k = k0 + i, n = n0 + tx;
    if (k < 784 && n < 2352) WT[(size_t)k * 2352 + n] = tile[tx][i];
  }
}

// ---------------------------------------------------------------------------
// GRU recurrent dots: gh[b,n] = sum_k h[b,k] * WhhT[k,n], b in [bh*4, bh*4+4)
// grid (37, 2), block 256 = 64 n x 4 b. Coalesced weight reads, LDS h broadcast.
// ---------------------------------------------------------------------------
__global__ __launch_bounds__(256) void gru_dots(const float* __restrict__ WT,
                                                const float* __restrict__ h,
                                                float* __restrict__ gh) {
  __shared__ float sh[4 * 784];
  const int tid = threadIdx.x;
  const int bh = blockIdx.y;
  const int bloc = tid >> 6;
  const int b = bh * 4 + bloc;
  const int n = blockIdx.x * 64 + (tid & 63);
  for (int u = tid; u < 3136; u += 256) sh[u] = h[bh * 3136 + u];
  __syncthreads();
  if (n >= 2352) return;
  const float4* h4 = (const float4*)(sh + bloc * 784);
  const float* wp = WT + n;
  float acc = 0.f;
#pragma unroll 2
  for (int kk = 0; kk < 196; ++kk) {
    float4 hv = h4[kk];
    const float* w = wp + (size_t)(kk * 4) * 2352;
    acc += hv.x * w[0];
    acc += hv.y * w[2352];
    acc += hv.z * w[4704];
    acc += hv.w * w[7056];
  }
  gh[b * 2352 + n] = acc;
}

// ---------------------------------------------------------------------------
// GRU gate combine: h_new from GI row s, gh, bhh. 6272 items.
// ---------------------------------------------------------------------------
__global__ __launch_bounds__(256) void gru_combine(const float* __restrict__ GI,
                                                   const float* __restrict__ gh,
                                                   const float* __restrict__ bhh,
                                                   const float* __restrict__ h_in,
                                                   float* __restrict__ h_out,
                                                   float* __restrict__ pref,
                                                   int s) {
  const int g = blockIdx.x * 256 + threadIdx.x;
  if (g >= 6272) return;
  const int b = g / 784;
  const int j = g - b * 784;
  const int bs = b * 32 + s;
  const float* gi = GI + (size_t)bs * 2352;
  const float* ghb = gh + b * 2352;
  float ghr = ghb[j] + bhh[j];
  float ghz = ghb[784 + j] + bhh[784 + j];
  float ghn = ghb[1568 + j] + bhh[1568 + j];
  float r = 1.f / (1.f + __expf(-(gi[j] + ghr)));
  float z = 1.f / (1.f + __expf(-(gi[784 + j] + ghz)));
  float nn = tanh_fast(gi[1568 + j] + r * ghn);
  float hn = (1.f - z) * nn + z * h_in[g];
  h_out[g] = hn;
  pref[(size_t)bs * 784 + j] = hn;
}

// ---------------------------------------------------------------------------
// Motion BN stats over 256 distinct rows
// ---------------------------------------------------------------------------
__global__ __launch_bounds__(128) void mot_stats(const float* __restrict__ mot,
                                                 float* __restrict__ msum,
                                                 float* __restrict__ msq) {
  int m = threadIdx.x;
  float s = 0.f, q = 0.f;
  for (int r = 0; r < 256; ++r) {
    float v = mot[r * 128 + m];
    s += v;
    q += v * v;
  }
  msum[m] = s;
  msq[m] = q;
}

// ---------------------------------------------------------------------------
// attn_scores via bf16 MFMA 16x16x32. One block per t.
//   C[m,n] = sum_c Wv[m,c]*video[t,c,n]; scores[n] = Wpvb + sum_m wpv[m]*tanh(C+pa[m])
// Block tile 128m x 224n (196 padded), K 528 padded to 544, slabs of 32.
// Waves 2x2 over (m,n): wave = 64m x 112n = 4 m-frags x 7 n-frags.
// LDS: sA[m][k] stride 40 bf16 (unswizzled); sB[n][k] stride 40 bf16 with
// XOR-pair swizzle (pair p stored at p ^ ((n&3)<<2)) to break write conflicts.
// ---------------------------------------------------------------------------
__global__ __launch_bounds__(256, 2) void attn_scores_mfma(
    const float* __restrict__ video, const float* __restrict__ Wv,
    const float* __restrict__ Wvb, const float* __restrict__ patt,
    const float* __restrict__ Wpv, const float* __restrict__ Wpvb,
    float* __restrict__ scores) {
  __shared__ short sA[128 * 40];
  __shared__ short sB[224 * 40];
  __shared__ float pa[128];
  __shared__ float wpv[128];
  __shared__ float ssc[224];

  const int t = blockIdx.x;
  const int bs = t / 5;
  const int tid = threadIdx.x;
  const int wave = tid >> 6;
  const int lane = tid & 63;
  const int q = lane >> 4;
  const int ln = lane & 15;
  const int wm = wave >> 1;   // 0..1  (m half)
  const int wn = wave & 1;    // 0..1  (n half)

  if (tid < 128) {
    pa[tid] = Wvb[tid] + patt[(size_t)bs * 128 + tid];
    wpv[tid] = Wpv[tid];
  }
  if (tid < 224) ssc[tid] = 0.f;

  f32x4 acc[4][7];
#pragma unroll
  for (int i = 0; i < 4; ++i)
#pragma unroll
    for (int j = 0; j < 7; ++j) acc[i][j] = (f32x4){0.f, 0.f, 0.f, 0.f};

  const float* vbase = video + (size_t)t * 103488;

  for (int c0 = 0; c0 < 544; c0 += 32) {
    // stage A: 128 m x 16 pairs (2 k each)
    for (int u = tid; u < 2048; u += 256) {
      int m = u >> 4, p = u & 15;
      int c = c0 + 2 * p;
      float f0 = (c < 528) ? Wv[m * 528 + c] : 0.f;
      float f1 = (c + 1 < 528) ? Wv[m * 528 + c + 1] : 0.f;
      unsigned pack = bf16r(f0) | (bf16r(f1) << 16);
      *(unsigned*)&sA[m * 40 + 2 * p] = pack;
    }
    // stage B (transpose + cvt): 224 n x 16 pairs; n fastest for coalescing
    for (int u = tid; u < 3584; u += 256) {
      int p = u / 224;
      int n = u - p * 224;
      int c = c0 + 2 * p;
      float f0 = 0.f, f1 = 0.f;
      if (n < 196) {
        if (c < 528) f0 = vbase[(size_t)c * 196 + n];
        if (c + 1 < 528) f1 = vbase[(size_t)(c + 1) * 196 + n];
      }
      unsigned pack = bf16r(f0) | (bf16r(f1) << 16);
      int pc = p ^ ((n & 3) << 2);
      *(unsigned*)&sB[n * 40 + 2 * pc] = pack;
    }
    __syncthreads();

    short8 afr[4], bfr[7];
#pragma unroll
    for (int mi = 0; mi < 4; ++mi) {
      int m = wm * 64 + mi * 16 + ln;
      afr[mi] = *(const short8*)&sA[m * 40 + q * 8];
    }
#pragma unroll
    for (int nj = 0; nj < 7; ++nj) {
      int n = wn * 112 + nj * 16 + ln;
      int p0 = (q * 4) ^ ((n & 3) << 2);
      bfr[nj] = *(const short8*)&sB[n * 40 + 2 * p0];
    }
#pragma unroll
    for (int mi = 0; mi < 4; ++mi)
#pragma unroll
      for (int nj = 0; nj < 7; ++nj)
        acc[mi][nj] = __builtin_amdgcn_mfma_f32_16x16x32_bf16(
            afr[mi], bfr[nj], acc[mi][nj], 0, 0, 0);
    __syncthreads();
  }

  // epilogue: contrib[n] = sum over this lane's 16 m values
  float contrib[7] = {};
#pragma unroll
  for (int mi = 0; mi < 4; ++mi)
#pragma unroll
    for (int r = 0; r < 4; ++r) {
      int m = wm * 64 + mi * 16 + q * 4 + r;
      float w = wpv[m];
      float bia = pa[m];
#pragma unroll
      for (int nj = 0; nj < 7; ++nj)
        contrib[nj] += w * tanh_fast(acc[mi][nj][r] + bia);
    }
#pragma unroll
  for (int nj = 0; nj < 7; ++nj)
    atomicAdd(&ssc[wn * 112 + nj * 16 + ln], contrib[nj]);
  __syncthreads();
  if (tid < 196) scores[(size_t)t * 196 + tid] = ssc[tid] + Wpvb[0];
}

// ---------------------------------------------------------------------------
// Pass 2: softmax + 1x1 conv on the other view + BN stats accumulation
// ---------------------------------------------------------------------------
__global__ __launch_bounds__(256) void attn_conv(
    const float* __restrict__ video, const float* __restrict__ scores,
    const float* __restrict__ convw, const float* __restrict__ convb,
    float* __restrict__ vid_pre, float* __restrict__ vstats) {
  __shared__ float red[256];
  __shared__ float att[196];
  __shared__ float scw[4 * 528];
  __shared__ float pre[784];

  const int t = blockIdx.x;
  const int tid = threadIdx.x;
  for (int u = tid; u < 2112; u += 256) scw[u] = convw[u];

  float v = (tid < 196) ? scores[(size_t)t * 196 + tid] : -FLT_MAX;
  red[tid] = v;
  __syncthreads();
  for (int st = 128; st > 0; st >>= 1) {
    if (tid < st) red[tid] = fmaxf(red[tid], red[tid + st]);
    __syncthreads();
  }
  float mx = red[0];
  __syncthreads();
  float e = (tid < 196) ? __expf(v - mx) : 0.f;
  red[tid] = e;
  __syncthreads();
  for (int st = 128; st > 0; st >>= 1) {
    if (tid < st) red[tid] += red[tid + st];
    __syncthreads();
  }
  float tot = red[0];
  if (tid < 196) att[tid] = e / tot;
  __syncthreads();

  const int lane = tid & 63;
  const int wv = tid >> 6;
  const float* vb = video + (size_t)t * 103488;
  for (int n = wv; n < 196; n += 4) {
    float s0 = 0.f, s1 = 0.f, s2 = 0.f, s3 = 0.f;
    for (int c = lane; c < 528; c += 64) {
      float x = vb[(size_t)n * 528 + c];
      s0 += x * scw[c];
      s1 += x * scw[528 + c];
      s2 += x * scw[1056 + c];
      s3 += x * scw[1584 + c];
    }
#pragma unroll
    for (int off = 32; off > 0; off >>= 1) {
      s0 += __shfl_down(s0, off);
      s1 += __shfl_down(s1, off);
      s2 += __shfl_down(s2, off);
      s3 += __shfl_down(s3, off);
    }
    if (lane == 0) {
      float a = att[n];
      pre[0 * 196 + n] = a * s0 + convb[0];
      pre[1 * 196 + n] = a * s1 + convb[1];
      pre[2 * 196 + n] = a * s2 + convb[2];
      pre[3 * 196 + n] = a * s3 + convb[3];
    }
  }
  __syncthreads();

  float ls[4] = {0.f, 0.f, 0.f, 0.f};
  float lq[4] = {0.f, 0.f, 0.f, 0.f};
  for (int u = tid; u < 784; u += 256) {
    float x = pre[u];
    vid_pre[(size_t)t * 784 + u] = x;
    int o = u / 196;
#pragma unroll
    for (int oo = 0; oo < 4; ++oo) {
      ls[oo] += (o == oo) ? x : 0.f;
      lq[oo] += (o == oo) ? x * x : 0.f;
    }
  }
#pragma unroll
  for (int oo = 0; oo < 4; ++oo)
#pragma unroll
    for (int off = 32; off > 0; off >>= 1) {
      ls[oo] += __shfl_down(ls[oo], off);
      lq[oo] += __shfl_down(lq[oo], off);
    }
  if (lane == 0)
#pragma unroll
    for (int oo = 0; oo < 4; ++oo) {
      atomicAdd(&vstats[oo], ls[oo]);
      atomicAdd(&vstats[4 + oo], lq[oo]);
    }
}

// ---------------------------------------------------------------------------
// Final assembly [1280, 1697]
// ---------------------------------------------------------------------------
__global__ __launch_bounds__(256) void finalize(
    const float* __restrict__ tw, const float* __restrict__ prefb,
    const float* __restrict__ motl, const float* __restrict__ msum,
    const float* __restrict__ msq, const float* __restrict__ mg,
    const float* __restrict__ mb, const float* __restrict__ vid_pre,
    const float* __restrict__ vstats, const float* __restrict__ vg,
    const float* __restrict__ vbb, float* __restrict__ out) {
  int g = blockIdx.x * 256 + threadIdx.x;
  if (g >= 1280 * 1697) return;
  int t = g / 1697;
  int col = g - t * 1697;
  int bs = t / 5;
  int p = t - bs * 5;
  float r;
  if (col == 0) {
    r = tw[p];
  } else if (col < 785) {
    r = prefb[(size_t)bs * 784 + (col - 1)];
  } else if (col < 913) {
    int m = col - 785;
    float x = motl[(size_t)bs * 128 + m];
    float mu = msum[m] * (1.f / 256.f);
    float var = msq[m] * (1.f / 256.f) - mu * mu;
    float y = (x - mu) * rsqrtf(var + 1e-5f) * mg[m] + mb[m];
    r = fmaxf(y, 0.f);
  } else {
    int qd = col - 913;
    int o = qd / 196;
    float x = vid_pre[(size_t)t * 784 + qd];
    float mu = vstats[o] * (1.f / 250880.f);
    float var = vstats[4 + o] * (1.f / 250880.f) - mu * mu;
    float y = (x - mu) * rsqrtf(var + 1e-5f) * vg[o] + vbb[o];
    r = fmaxf(y, 0.f);
  }
  out[g] = r;
}

// ---------------------------------------------------------------------------
extern "C" void kernel_launch(void* const* d_in, const int* in_sizes, int n_in,
                              void* d_out, int out_size, void* d_ws,
                              size_t ws_size, hipStream_t stream) {
  const float* fov = (const float*)d_in[0];
  const float* motion = (const float*)d_in[1];
  const float* video = (const float*)d_in[2];
  const float* timew = (const float*)d_in[3];
  const float* w_ih = (const float*)d_in[4];
  const float* w_hh = (const float*)d_in[5];
  const float* b_ih = (const float*)d_in[6];
  const float* b_hh = (const float*)d_in[7];
  const float* Wp = (const float*)d_in[8];
  const float* Wv_w = (const float*)d_in[9];
  const float* Wv_b = (const float*)d_in[10];
  const float* Wpv_w = (const float*)d_in[11];
  const float* Wpv_b = (const float*)d_in[12];
  const float* conv_w = (const float*)d_in[13];
  const float* conv_b = (const float*)d_in[14];
  const float* vbn_g = (const float*)d_in[15];
  const float* vbn_b = (const float*)d_in[16];
  const float* me_w = (const float*)d_in[17];
  const float* me_b = (const float*)d_in[18];
  const float* mbn_g = (const float*)d_in[19];
  const float* mbn_b = (const float*)d_in[20];

  float* ws = (float*)d_ws;
  float* h0b = ws + 0;             // 6272
  float* stats = ws + 6272;        // 264
  float* msum = stats;
  float* msq = stats + 128;
  float* vstats = stats + 256;
  float* h1b = ws + 6656;          // 6272
  float* gh = ws + 12928;          // 18816
  float* GI = ws + 31744;          // 602112
  float* prefb = ws + 633856;      // 200704
  float* patt = ws + 834560;       // 32768
  float* motl = ws + 867328;       // 32768
  float* scores = ws + 900096;     // 250880
  float* vid_pre = ws + 1150976;   // 1003520
  float* WT = ws + 2154496;        // 1843968  (total ~16.0 MB)

  // zero h0 + stats accumulators
  hipMemsetAsync(ws, 0, 6536 * sizeof(float), stream);

  whh_transpose<<<dim3(74, 25), 256, 0, stream>>>(w_hh, WT);

  // GRU input projection: GI[256,2352]
  gemm_nt<<<dim3((2352 + GT_BN - 1) / GT_BN, 256 / GT_BM), 256, 0, stream>>>(
      fov, w_ih, b_ih, GI, 256, 2352, 528);

  for (int s = 0; s < 32; ++s) {
    const float* hin = (s & 1) ? h1b : h0b;
    float* hout = (s & 1) ? h0b : h1b;
    gru_dots<<<dim3(37, 2), 256, 0, stream>>>(WT, hin, gh);
    gru_combine<<<25, 256, 0, stream>>>(GI, gh, b_hh, hin, hout, prefb, s);
  }

  gemm_nt<<<dim3(2, 8), 256, 0, stream>>>(prefb, Wp, nullptr, patt, 256, 128, 784);
  gemm_nt<<<dim3(2, 8), 256, 0, stream>>>(motion, me_w, me_b, motl, 256, 128, 90);
  mot_stats<<<1, 128, 0, stream>>>(motl, msum, msq);

  attn_scores_mfma<<<1280, 256, 0, stream>>>(video, Wv_w, Wv_b, patt, Wpv_w,
                                             Wpv_b, scores);
  attn_conv<<<1280, 256, 0, stream>>>(video, scores, conv_w, conv_b, vid_pre,
                                      vstats);

  int total = 1280 * 1697;
  finalize<<<(total + 255) / 256, 256, 0, stream>>>(
      timew, prefb, motl, msum, msq, mbn_g, mbn_b, vid_pre, vstats, vbn_g,
      vbn_b, (float*)d_out);
}